// Round 11
// baseline (335.660 us; speedup 1.0000x reference)
//
#include <hip/hip_runtime.h>
#include <stdint.h>

typedef unsigned short u16;
typedef __attribute__((ext_vector_type(8))) short bf16x8;   // 8 bf16 = 4 VGPRs
typedef __attribute__((ext_vector_type(4))) float f32x4;

#define QSCL 0.1803368801111244f   /* 0.125 * log2(e): folded into Q */

#define GLD_LDS16(g, l) __builtin_amdgcn_global_load_lds( \
    (const __attribute__((address_space(1))) void*)(g),    \
    (__attribute__((address_space(3))) void*)(l), 16, 0, 0)

__device__ __forceinline__ u16 f2bf(float f) {
    union { uint32_t i; float f; } v; v.f = f;
    uint32_t i = v.i;
    return (u16)((i + 0x7FFFu + ((i >> 16) & 1u)) >> 16);
}
__device__ __forceinline__ uint32_t fbits(float f) {
    union { float f; uint32_t i; } v; v.f = f; return v.i;
}
__device__ __forceinline__ float bits2f(uint32_t i) {
    union { uint32_t i; float f; } v; v.i = i; return v.f;
}

// ---------------------------------------------------------------------------
// One-shot weight transpose: dst_bf16[C][R] = src_f32[R][C]^T. Tiny.
// ---------------------------------------------------------------------------
__global__ __launch_bounds__(256)
void transpose_kernel(const float* __restrict__ src, u16* __restrict__ dst,
                      int R, int Ctiles) {
    __shared__ u16 T[64][68];
    const int t = threadIdx.x;
    const int rt = blockIdx.x / Ctiles;
    const int ct = blockIdx.x % Ctiles;
    const int C = Ctiles << 6;

    for (int i = 0; i < 4; i++) {
        int idx = t + 256 * i;
        int row = idx >> 4;
        int col4 = (idx & 15) << 2;
        float4 d = *(const float4*)(src + (size_t)(rt * 64 + row) * C + ct * 64 + col4);
        T[col4 + 0][row] = f2bf(d.x);
        T[col4 + 1][row] = f2bf(d.y);
        T[col4 + 2][row] = f2bf(d.z);
        T[col4 + 3][row] = f2bf(d.w);
    }
    __syncthreads();
    for (int i = 0; i < 4; i++) {
        int idx = t + 256 * i;
        int row = idx >> 4;
        int col4 = (idx & 15) << 2;
        uint2 d = *(const uint2*)&T[row][col4];
        *(uint2*)(dst + (size_t)(ct * 64 + row) * R + rt * 64 + col4) = d;
    }
}

// ---------------------------------------------------------------------------
// fp32 -> bf16 convert: xbf[i] = bf16(x[i]). 4 elems/thread.
// ---------------------------------------------------------------------------
__global__ __launch_bounds__(256)
void convert_kernel(const float* __restrict__ x, u16* __restrict__ xbf) {
    size_t i = ((size_t)blockIdx.x * 256 + threadIdx.x) * 4;
    float4 d = *(const float4*)(x + i);
    u16 e[4] = {f2bf(d.x), f2bf(d.y), f2bf(d.z), f2bf(d.w)};
    *(uint2*)(xbf + i) = *(uint2*)e;
}

// ===========================================================================
// OLD-STYLE GEMMs (fallback tier, proven): 64x64 tile, VALU staging.
// ===========================================================================
__global__ __launch_bounds__(256)
void gemm_qkv_old(const float* __restrict__ X, const u16* __restrict__ Wt,
                  const float* __restrict__ Bias, u16* __restrict__ QK,
                  u16* __restrict__ Vt) {
    __shared__ __align__(16) u16 As[64][40];
    __shared__ __align__(16) u16 Bts[64][40];

    const int t = threadIdx.x;
    const int lane = t & 63;
    const int wave = t >> 6;
    const int l15 = lane & 15;
    const int l4 = lane >> 4;

    const int ntile = blockIdx.x % 12;
    const int mbase = (blockIdx.x / 12) << 6;

    f32x4 acc[4];
    for (int c = 0; c < 4; c++) acc[c] = (f32x4){0.f, 0.f, 0.f, 0.f};

    for (int kc = 0; kc < 256; kc += 32) {
        __syncthreads();
        for (int i = 0; i < 2; i++) {
            int idx = t + 256 * i;
            int row = idx >> 3;
            int col4 = (idx & 7) << 2;
            float4 d = *(const float4*)(X + (size_t)(mbase + row) * 256 + kc + col4);
            u16 e[4] = {f2bf(d.x), f2bf(d.y), f2bf(d.z), f2bf(d.w)};
            *(uint2*)&As[row][col4] = *(uint2*)e;
        }
        for (int i = 0; i < 2; i++) {
            int idx = t + 256 * i;
            int row = idx >> 3;
            int col4 = (idx & 7) << 2;
            uint2 w = *(const uint2*)(Wt + (size_t)(ntile * 64 + row) * 256 + kc + col4);
            *(uint2*)&Bts[row][col4] = w;
        }
        __syncthreads();

        bf16x8 a = *(const bf16x8*)&As[wave * 16 + l15][l4 * 8];
        for (int c = 0; c < 4; c++) {
            bf16x8 b = *(const bf16x8*)&Bts[c * 16 + l15][l4 * 8];
            acc[c] = __builtin_amdgcn_mfma_f32_16x16x32_bf16(a, b, acc[c], 0, 0, 0);
        }
    }

    if (ntile < 8) {
        const float scl = (ntile < 4) ? QSCL : 1.0f;
        for (int c = 0; c < 4; c++) {
            int colc = c * 16 + l15;
            float bv = Bias[ntile * 64 + colc];
            for (int r = 0; r < 4; r++) {
                int row = mbase + wave * 16 + l4 * 4 + r;
                QK[(size_t)row * 512 + ntile * 64 + colc] = f2bf((acc[c][r] + bv) * scl);
            }
        }
    } else {
        const int h = ntile - 8;
        for (int c = 0; c < 4; c++) {
            int d = c * 16 + l15;
            float bv = Bias[512 + h * 64 + d];
            int n = mbase + wave * 16 + l4 * 4;
            int b = n >> 12;
            int nin = n & 4095;
            u16 e[4] = {f2bf(acc[c][0] + bv), f2bf(acc[c][1] + bv),
                        f2bf(acc[c][2] + bv), f2bf(acc[c][3] + bv)};
            *(uint2*)(Vt + ((size_t)(b * 4 + h) * 64 + d) * 4096 + nin) = *(uint2*)e;
        }
    }
}

__global__ __launch_bounds__(256)
void gemm_out_old(const u16* __restrict__ Wt2, const float* __restrict__ Bias,
                  float* __restrict__ IO) {
    __shared__ __align__(16) u16 As[64][264];
    __shared__ __align__(16) u16 Wts[256][40];

    const int t = threadIdx.x;
    const int lane = t & 63;
    const int wave = t >> 6;
    const int l15 = lane & 15;
    const int l4 = lane >> 4;
    const int mbase = blockIdx.x << 6;

    for (int i = 0; i < 16; i++) {
        int idx = t + 256 * i;
        int row = idx >> 6;
        int col4 = (idx & 63) << 2;
        float4 d = *(const float4*)(IO + (size_t)(mbase + row) * 256 + col4);
        u16 e[4] = {f2bf(d.x), f2bf(d.y), f2bf(d.z), f2bf(d.w)};
        *(uint2*)&As[row][col4] = *(uint2*)e;
    }

    f32x4 acc[4][4];
    for (int nt = 0; nt < 4; nt++)
        for (int c = 0; c < 4; c++) acc[nt][c] = (f32x4){0.f, 0.f, 0.f, 0.f};

    for (int kc = 0; kc < 256; kc += 32) {
        __syncthreads();
        for (int i = 0; i < 8; i++) {
            int idx = t + 256 * i;
            int row = idx >> 3;
            int col4 = (idx & 7) << 2;
            uint2 w = *(const uint2*)(Wt2 + (size_t)row * 256 + kc + col4);
            *(uint2*)&Wts[row][col4] = w;
        }
        __syncthreads();

        bf16x8 a = *(const bf16x8*)&As[wave * 16 + l15][kc + l4 * 8];
        for (int nt = 0; nt < 4; nt++)
            for (int c = 0; c < 4; c++) {
                bf16x8 b = *(const bf16x8*)&Wts[nt * 64 + c * 16 + l15][l4 * 8];
                acc[nt][c] = __builtin_amdgcn_mfma_f32_16x16x32_bf16(a, b, acc[nt][c], 0, 0, 0);
            }
    }

    for (int nt = 0; nt < 4; nt++)
        for (int c = 0; c < 4; c++) {
            int coln = nt * 64 + c * 16 + l15;
            float bv = Bias[coln];
            for (int r = 0; r < 4; r++) {
                int row = mbase + wave * 16 + l4 * 4 + r;
                IO[(size_t)row * 256 + coln] = acc[nt][c][r] + bv;
            }
        }
}

// ===========================================================================
// NEW m97-style GEMM core (proven last round): global_load_lds staging,
// XOR-swizzled chunks, ds_read_b128 frags, 16 MFMA/wave/K-step.
// ===========================================================================
__global__ __launch_bounds__(256)
void gemm_qkv_new(const u16* __restrict__ Abf, const u16* __restrict__ Bt,
                  const float* __restrict__ Bias, u16* __restrict__ QK,
                  u16* __restrict__ Vt) {
    __shared__ __align__(16) u16 As[128 * 32];
    __shared__ __align__(16) u16 Bs[128 * 32];

    const int t = threadIdx.x;
    const int lane = t & 63;
    const int wave = t >> 6;
    const int l15 = lane & 15;
    const int l4 = lane >> 4;
    const int wm = wave >> 1, wn = wave & 1;

    const int mb = blockIdx.x / 6;
    const int nb = blockIdx.x % 6;

    const u16* gA[2]; const u16* gB[2]; int ldsoff[2];
    #pragma unroll
    for (int i = 0; i < 2; i++) {
        int chunk = i * 256 + t;
        int row = chunk >> 2;
        int sch = (chunk & 3) ^ (row & 3);
        gA[i] = Abf + (size_t)(mb * 128 + row) * 256 + sch * 8;
        gB[i] = Bt + (size_t)(nb * 128 + row) * 256 + sch * 8;
        ldsoff[i] = (i * 256 + wave * 64) * 8;
    }
    int offA[4], offB[4];
    #pragma unroll
    for (int c = 0; c < 4; c++) {
        offA[c] = (wm * 64 + c * 16 + l15) * 32 + ((l4 ^ (l15 & 3)) * 8);
        offB[c] = (wn * 64 + c * 16 + l15) * 32 + ((l4 ^ (l15 & 3)) * 8);
    }

    f32x4 acc[4][4];
    #pragma unroll
    for (int cm = 0; cm < 4; cm++)
        for (int cn = 0; cn < 4; cn++) acc[cm][cn] = (f32x4){0.f, 0.f, 0.f, 0.f};

    for (int kc = 0; kc < 256; kc += 32) {
        __syncthreads();
        #pragma unroll
        for (int i = 0; i < 2; i++) {
            GLD_LDS16(gA[i] + kc, As + ldsoff[i]);
            GLD_LDS16(gB[i] + kc, Bs + ldsoff[i]);
        }
        __syncthreads();

        bf16x8 a[4], b[4];
        #pragma unroll
        for (int c = 0; c < 4; c++) {
            a[c] = *(const bf16x8*)(As + offA[c]);
            b[c] = *(const bf16x8*)(Bs + offB[c]);
        }
        #pragma unroll
        for (int cm = 0; cm < 4; cm++)
            #pragma unroll
            for (int cn = 0; cn < 4; cn++)
                acc[cm][cn] = __builtin_amdgcn_mfma_f32_16x16x32_bf16(
                    a[cm], b[cn], acc[cm][cn], 0, 0, 0);
    }

    #pragma unroll
    for (int cn = 0; cn < 4; cn++) {
        int n = nb * 128 + wn * 64 + cn * 16 + l15;
        float bv = Bias[n];
        int slice = n >> 6;
        if (slice < 4) {
            #pragma unroll
            for (int cm = 0; cm < 4; cm++) {
                int m0 = mb * 128 + wm * 64 + cm * 16 + l4 * 4;
                for (int r = 0; r < 4; r++)
                    QK[(size_t)(m0 + r) * 512 + n] = f2bf((acc[cm][cn][r] + bv) * QSCL);
            }
        } else if (slice < 8) {
            #pragma unroll
            for (int cm = 0; cm < 4; cm++) {
                int m0 = mb * 128 + wm * 64 + cm * 16 + l4 * 4;
                for (int r = 0; r < 4; r++)
                    QK[(size_t)(m0 + r) * 512 + n] = f2bf(acc[cm][cn][r] + bv);
            }
        } else {
            int h = slice - 8;
            int d = n & 63;
            #pragma unroll
            for (int cm = 0; cm < 4; cm++) {
                int m0 = mb * 128 + wm * 64 + cm * 16 + l4 * 4;
                int b_ = m0 >> 12;
                int nin = m0 & 4095;
                u16 e[4] = {f2bf(acc[cm][cn][0] + bv), f2bf(acc[cm][cn][1] + bv),
                            f2bf(acc[cm][cn][2] + bv), f2bf(acc[cm][cn][3] + bv)};
                *(uint2*)(Vt + ((size_t)(b_ * 4 + h) * 64 + d) * 4096 + nin) = *(uint2*)e;
            }
        }
    }
}

__global__ __launch_bounds__(256)
void gemm_out_new(const u16* __restrict__ Obf, const u16* __restrict__ Wt2,
                  const float* __restrict__ Bias, float* __restrict__ out) {
    __shared__ __align__(16) u16 As[128 * 32];
    __shared__ __align__(16) u16 Bs[128 * 32];

    const int t = threadIdx.x;
    const int lane = t & 63;
    const int wave = t >> 6;
    const int l15 = lane & 15;
    const int l4 = lane >> 4;
    const int wm = wave >> 1, wn = wave & 1;

    const int mb = blockIdx.x >> 1;
    const int nb = blockIdx.x & 1;

    const u16* gA[2]; const u16* gB[2]; int ldsoff[2];
    #pragma unroll
    for (int i = 0; i < 2; i++) {
        int chunk = i * 256 + t;
        int row = chunk >> 2;
        int sch = (chunk & 3) ^ (row & 3);
        gA[i] = Obf + (size_t)(mb * 128 + row) * 256 + sch * 8;
        gB[i] = Wt2 + (size_t)(nb * 128 + row) * 256 + sch * 8;
        ldsoff[i] = (i * 256 + wave * 64) * 8;
    }
    int offA[4], offB[4];
    #pragma unroll
    for (int c = 0; c < 4; c++) {
        offA[c] = (wm * 64 + c * 16 + l15) * 32 + ((l4 ^ (l15 & 3)) * 8);
        offB[c] = (wn * 64 + c * 16 + l15) * 32 + ((l4 ^ (l15 & 3)) * 8);
    }

    f32x4 acc[4][4];
    #pragma unroll
    for (int cm = 0; cm < 4; cm++)
        for (int cn = 0; cn < 4; cn++) acc[cm][cn] = (f32x4){0.f, 0.f, 0.f, 0.f};

    for (int kc = 0; kc < 256; kc += 32) {
        __syncthreads();
        #pragma unroll
        for (int i = 0; i < 2; i++) {
            GLD_LDS16(gA[i] + kc, As + ldsoff[i]);
            GLD_LDS16(gB[i] + kc, Bs + ldsoff[i]);
        }
        __syncthreads();

        bf16x8 a[4], b[4];
        #pragma unroll
        for (int c = 0; c < 4; c++) {
            a[c] = *(const bf16x8*)(As + offA[c]);
            b[c] = *(const bf16x8*)(Bs + offB[c]);
        }
        #pragma unroll
        for (int cm = 0; cm < 4; cm++)
            #pragma unroll
            for (int cn = 0; cn < 4; cn++)
                acc[cm][cn] = __builtin_amdgcn_mfma_f32_16x16x32_bf16(
                    a[cm], b[cn], acc[cm][cn], 0, 0, 0);
    }

    #pragma unroll
    for (int cn = 0; cn < 4; cn++) {
        int n = nb * 128 + wn * 64 + cn * 16 + l15;
        float bv = Bias[n];
        #pragma unroll
        for (int cm = 0; cm < 4; cm++) {
            int m0 = mb * 128 + wm * 64 + cm * 16 + l4 * 4;
            for (int r = 0; r < 4; r++)
                out[(size_t)(m0 + r) * 256 + n] = acc[cm][cn][r] + bv;
        }
    }
}

// ---------------------------------------------------------------------------
// Flash attention: barrier-free all-register pipeline. 1 wave/block, 32 q.
// Both K and V double-buffered in VGPRs; per half-iteration strict order:
//   S-MFMA(current K/V)  <-- the ONE vmcnt wait point (loads a full iter old)
//   issue next V loads, then next K loads (no same-iter consumer)
//   softmax -> Ps LDS round-trip ordered by compiler barrier + lgkmcnt(0)
//   PV-MFMA(current V)   <-- regs already waited; no vmcnt interaction
// DS (lgkmcnt) and global (vmcnt) use different counters, so the Ps traffic
// cannot drain the prefetch (unlike __threadfence_block / __syncthreads).
// ---------------------------------------------------------------------------
__global__ __launch_bounds__(64, 2)
void attn_kernel(const u16* __restrict__ QK, const u16* __restrict__ Vt,
                 float* __restrict__ Of, u16* __restrict__ Obf, int writebf,
                 int bhmask, int bhbits) {
    __shared__ __align__(16) u16 Ps[2][16][76];   // [qset][q][j] pad 76

    const int lane = threadIdx.x;
    const int l15 = lane & 15;
    const int l4 = lane >> 4;

    const int bh = blockIdx.x & bhmask;      // head-major: L2 locality per XCD
    const int strip = blockIdx.x >> bhbits;  // 0..127
    const int b = bh >> 2;
    const int h = bh & 3;

    const size_t qkbase = (size_t)b * 4096 * 512;
    const size_t vtbase = (size_t)bh * 64 * 4096;
    const int q0 = strip * 32;

    // Q fragments: registers for the whole kernel (B-operand, n = q = l15)
    bf16x8 qf[2][2];
    #pragma unroll
    for (int qs = 0; qs < 2; qs++)
        #pragma unroll
        for (int kk = 0; kk < 2; kk++)
            qf[qs][kk] = *(const bf16x8*)(QK + qkbase
                + (size_t)(q0 + qs * 16 + l15) * 512 + h * 64 + kk * 32 + l4 * 8);

    const u16* Kb = QK + qkbase + 256 + h * 64 + (size_t)l15 * 512 + l4 * 8;
    const u16* Vb = Vt + vtbase + (size_t)l15 * 4096 + l4 * 8;

    u16* pswr = &Ps[0][l15][l4 * 4];        // + qs*1216 + c*16
    const u16* psrd = &Ps[0][l15][l4 * 8];  // + qs*1216 + kk*32

    f32x4 Oacc[2][4];
    #pragma unroll
    for (int qs = 0; qs < 2; qs++)
        for (int c = 0; c < 4; c++) Oacc[qs][c] = (f32x4){0.f, 0.f, 0.f, 0.f};
    float lsum[2] = {0.f, 0.f};

    // register double buffers for K and V tiles (tile jt: 64 j x 64 d)
    bf16x8 ka[4][2], kb2[4][2], va[4][2], vb2[4][2];
    #pragma unroll
    for (int c = 0; c < 4; c++) {
        va[c][0] = *(const bf16x8*)(Vb + (size_t)c * 65536);        // c*16 d-rows
        va[c][1] = *(const bf16x8*)(Vb + (size_t)c * 65536 + 32);
        ka[c][0] = *(const bf16x8*)(Kb + (size_t)c * 8192);         // c*16 j-rows
        ka[c][1] = *(const bf16x8*)(Kb + (size_t)c * 8192 + 32);
    }

    auto half = [&](int jnext, bf16x8 (&kc)[4][2], bf16x8 (&vc)[4][2],
                    bf16x8 (&kn)[4][2], bf16x8 (&vn)[4][2]) {
        // 1) S^T from CURRENT K (single wait point; loads are one iter old)
        f32x4 s[2][4];
        #pragma unroll
        for (int qs = 0; qs < 2; qs++)
            for (int c = 0; c < 4; c++) s[qs][c] = (f32x4){0.f, 0.f, 0.f, 0.f};
        #pragma unroll
        for (int c = 0; c < 4; c++) {
            s[0][c] = __builtin_amdgcn_mfma_f32_16x16x32_bf16(kc[c][0], qf[0][0], s[0][c], 0, 0, 0);
            s[0][c] = __builtin_amdgcn_mfma_f32_16x16x32_bf16(kc[c][1], qf[0][1], s[0][c], 0, 0, 0);
            s[1][c] = __builtin_amdgcn_mfma_f32_16x16x32_bf16(kc[c][0], qf[1][0], s[1][c], 0, 0, 0);
            s[1][c] = __builtin_amdgcn_mfma_f32_16x16x32_bf16(kc[c][1], qf[1][1], s[1][c], 0, 0, 0);
        }

        // 2) prefetch NEXT tile: V first, then K (waiting K next iter => V done)
        const u16* vr = Vb + jnext * 64;
        const u16* kr = Kb + (size_t)jnext * 32768;
        #pragma unroll
        for (int c = 0; c < 4; c++) {
            vn[c][0] = *(const bf16x8*)(vr + (size_t)c * 65536);
            vn[c][1] = *(const bf16x8*)(vr + (size_t)c * 65536 + 32);
        }
        #pragma unroll
        for (int c = 0; c < 4; c++) {
            kn[c][0] = *(const bf16x8*)(kr + (size_t)c * 8192);
            kn[c][1] = *(const bf16x8*)(kr + (size_t)c * 8192 + 32);
        }

        // 3) softmax: p = exp2(s); truncation-consistent lsum; perm-packed Ps
        #pragma unroll
        for (int qs = 0; qs < 2; qs++) {
            float ls = 0.f;
            #pragma unroll
            for (int c = 0; c < 4; c++) {
                f32x4 sv = s[qs][c];
                uint32_t u0 = fbits(__builtin_exp2f(sv[0]));
                uint32_t u1 = fbits(__builtin_exp2f(sv[1]));
                uint32_t u2 = fbits(__builtin_exp2f(sv[2]));
                uint32_t u3 = fbits(__builtin_exp2f(sv[3]));
                float t0 = bits2f(u0 & 0xFFFF0000u);
                float t1 = bits2f(u1 & 0xFFFF0000u);
                float t2 = bits2f(u2 & 0xFFFF0000u);
                float t3 = bits2f(u3 & 0xFFFF0000u);
                ls += (t0 + t1) + (t2 + t3);
                uint2 pk;
                pk.x = __builtin_amdgcn_perm(u1, u0, 0x07060302u);
                pk.y = __builtin_amdgcn_perm(u3, u2, 0x07060302u);
                *(uint2*)(pswr + qs * 1216 + c * 16) = pk;
            }
            lsum[qs] += ls;
        }

        // 4) order Ps write->read: compiler barrier + lgkmcnt(0) ONLY
        //    (no vmcnt -> prefetch stays in flight)
        asm volatile("" ::: "memory");
        __builtin_amdgcn_s_waitcnt(0xc07f);   // lgkmcnt(0), vmcnt/exp untouched
        asm volatile("" ::: "memory");

        bf16x8 bp[2][2];
        #pragma unroll
        for (int qs = 0; qs < 2; qs++)
            #pragma unroll
            for (int kk = 0; kk < 2; kk++)
                bp[qs][kk] = *(const bf16x8*)(psrd + qs * 1216 + kk * 32);

        // 5) O^T += V^T P^T from CURRENT V (already waited at step 1)
        #pragma unroll
        for (int c = 0; c < 4; c++) {
            Oacc[0][c] = __builtin_amdgcn_mfma_f32_16x16x32_bf16(vc[c][0], bp[0][0], Oacc[0][c], 0, 0, 0);
            Oacc[0][c] = __builtin_amdgcn_mfma_f32_16x16x32_bf16(vc[c][1], bp[0][1], Oacc[0][c], 0, 0, 0);
            Oacc[1][c] = __builtin_amdgcn_mfma_f32_16x16x32_bf16(vc[c][0], bp[1][0], Oacc[1][c], 0, 0, 0);
            Oacc[1][c] = __builtin_amdgcn_mfma_f32_16x16x32_bf16(vc[c][1], bp[1][1], Oacc[1][c], 0, 0, 0);
        }
    };

    for (int jt = 0; jt < 64; jt += 2) {
        half(jt + 1, ka, va, kb2, vb2);
        half((jt + 2) & 63, kb2, vb2, ka, va);   // wrap: dead last prefetch in-bounds
    }

    // epilogue: Oacc[qs][c][r] = O^T[d=16c+4*l4+r][q=q0+qs*16+l15]
    #pragma unroll
    for (int qs = 0; qs < 2; qs++) {
        float l = lsum[qs];
        l += __shfl_xor(l, 16);
        l += __shfl_xor(l, 32);
        float inv = 1.f / l;
        size_t row = (size_t)b * 4096 + q0 + qs * 16 + l15;
        if (writebf) {
            #pragma unroll
            for (int c = 0; c < 4; c++) {
                f32x4 o = Oacc[qs][c] * inv;
                u16 e[4] = {f2bf(o[0]), f2bf(o[1]), f2bf(o[2]), f2bf(o[3])};
                *(uint2*)(Obf + row * 256 + h * 64 + c * 16 + l4 * 4) = *(uint2*)e;
            }
        } else {
            #pragma unroll
            for (int c = 0; c < 4; c++) {
                f32x4 o = Oacc[qs][c] * inv;
                *(f32x4*)(Of + row * 256 + h * 64 + c * 16 + l4 * 4) = o;
            }
        }
    }
}

// ---------------------------------------------------------------------------
extern "C" void kernel_launch(void* const* d_in, const int* in_sizes, int n_in,
                              void* d_out, int out_size, void* d_ws, size_t ws_size,
                              hipStream_t stream) {
    const float* x     = (const float*)d_in[0];  // [16384,256]
    const float* w_qkv = (const float*)d_in[1];  // [256,768]
    const float* b_qkv = (const float*)d_in[2];  // [768]
    const float* w_out = (const float*)d_in[3];  // [256,256]
    const float* b_out = (const float*)d_in[4];  // [256]
    float* out = (float*)d_out;                  // [16384,256] fp32

    char* ws = (char*)d_ws;
    u16* Wt  = (u16*)ws;                             // [768][256]   393216 B
    u16* Wt2 = (u16*)(ws + 393216);                  // [256][256]   131072 B
    u16* QK  = (u16*)(ws + 524288);                  // [16384][512] 16.78 MB
    u16* Vt  = (u16*)(ws + 524288 + 16777216);       // [16][64][4096] 8.39 MB
    u16* XO  = (u16*)(ws + 524288 + 16777216 + 8388608);  // xbf/Obf shared 8.39 MB
    const size_t NEED_NEW = 524288 + 16777216 + 8388608 + 8388608; // 34.08 MB

    transpose_kernel<<<dim3(48), dim3(256), 0, stream>>>(w_qkv, Wt, 256, 12);
    transpose_kernel<<<dim3(16), dim3(256), 0, stream>>>(w_out, Wt2, 256, 4);

    if (ws_size >= NEED_NEW) {
        convert_kernel<<<dim3(4096), dim3(256), 0, stream>>>(x, XO);
        gemm_qkv_new<<<dim3(768), dim3(256), 0, stream>>>(XO, Wt, b_qkv, QK, Vt);
        attn_kernel<<<dim3(2048), dim3(64), 0, stream>>>(
            QK, Vt, out, XO, 1, 15, 4);
        gemm_out_new<<<dim3(256), dim3(256), 0, stream>>>(XO, Wt2, b_out, out);
    } else {
        // fallback (proven 25.7 MB layout): old GEMMs, attn writes fp32
        gemm_qkv_old<<<dim3(3072), dim3(256), 0, stream>>>(x, Wt, b_qkv, QK, Vt);
        attn_kernel<<<dim3(2048), dim3(64), 0, stream>>>(
            QK, Vt, out, (u16*)nullptr, 0, 15, 4);
        gemm_out_old<<<dim3(256), dim3(256), 0, stream>>>(Wt2, b_out, out);
    }
}

// Round 12
// 220.964 us; speedup vs baseline: 1.5191x; 1.5191x over previous
//
#include <hip/hip_runtime.h>
#include <stdint.h>

typedef unsigned short u16;
typedef __attribute__((ext_vector_type(8))) short bf16x8;   // 8 bf16 = 4 VGPRs
typedef __attribute__((ext_vector_type(4))) float f32x4;

#define QSCL 0.1803368801111244f   /* 0.125 * log2(e): folded into Q */

#define GLD_LDS16(g, l) __builtin_amdgcn_global_load_lds( \
    (const __attribute__((address_space(1))) void*)(g),    \
    (__attribute__((address_space(3))) void*)(l), 16, 0, 0)

__device__ __forceinline__ u16 f2bf(float f) {
    union { uint32_t i; float f; } v; v.f = f;
    uint32_t i = v.i;
    return (u16)((i + 0x7FFFu + ((i >> 16) & 1u)) >> 16);
}
__device__ __forceinline__ uint32_t fbits(float f) {
    union { float f; uint32_t i; } v; v.f = f; return v.i;
}
__device__ __forceinline__ float bits2f(uint32_t i) {
    union { uint32_t i; float f; } v; v.i = i; return v.f;
}

// ---------------------------------------------------------------------------
// One-shot weight transpose: dst_bf16[C][R] = src_f32[R][C]^T. Tiny.
// ---------------------------------------------------------------------------
__global__ __launch_bounds__(256)
void transpose_kernel(const float* __restrict__ src, u16* __restrict__ dst,
                      int R, int Ctiles) {
    __shared__ u16 T[64][68];
    const int t = threadIdx.x;
    const int rt = blockIdx.x / Ctiles;
    const int ct = blockIdx.x % Ctiles;
    const int C = Ctiles << 6;

    for (int i = 0; i < 4; i++) {
        int idx = t + 256 * i;
        int row = idx >> 4;
        int col4 = (idx & 15) << 2;
        float4 d = *(const float4*)(src + (size_t)(rt * 64 + row) * C + ct * 64 + col4);
        T[col4 + 0][row] = f2bf(d.x);
        T[col4 + 1][row] = f2bf(d.y);
        T[col4 + 2][row] = f2bf(d.z);
        T[col4 + 3][row] = f2bf(d.w);
    }
    __syncthreads();
    for (int i = 0; i < 4; i++) {
        int idx = t + 256 * i;
        int row = idx >> 4;
        int col4 = (idx & 15) << 2;
        uint2 d = *(const uint2*)&T[row][col4];
        *(uint2*)(dst + (size_t)(ct * 64 + row) * R + rt * 64 + col4) = d;
    }
}

// ---------------------------------------------------------------------------
// fp32 -> bf16 convert: xbf[i] = bf16(x[i]). 4 elems/thread.
// ---------------------------------------------------------------------------
__global__ __launch_bounds__(256)
void convert_kernel(const float* __restrict__ x, u16* __restrict__ xbf) {
    size_t i = ((size_t)blockIdx.x * 256 + threadIdx.x) * 4;
    float4 d = *(const float4*)(x + i);
    u16 e[4] = {f2bf(d.x), f2bf(d.y), f2bf(d.z), f2bf(d.w)};
    *(uint2*)(xbf + i) = *(uint2*)e;
}

// ===========================================================================
// OLD-STYLE GEMMs (fallback tier, proven): 64x64 tile, VALU staging.
// ===========================================================================
__global__ __launch_bounds__(256)
void gemm_qkv_old(const float* __restrict__ X, const u16* __restrict__ Wt,
                  const float* __restrict__ Bias, u16* __restrict__ QK,
                  u16* __restrict__ Vt) {
    __shared__ __align__(16) u16 As[64][40];
    __shared__ __align__(16) u16 Bts[64][40];

    const int t = threadIdx.x;
    const int lane = t & 63;
    const int wave = t >> 6;
    const int l15 = lane & 15;
    const int l4 = lane >> 4;

    const int ntile = blockIdx.x % 12;
    const int mbase = (blockIdx.x / 12) << 6;

    f32x4 acc[4];
    for (int c = 0; c < 4; c++) acc[c] = (f32x4){0.f, 0.f, 0.f, 0.f};

    for (int kc = 0; kc < 256; kc += 32) {
        __syncthreads();
        for (int i = 0; i < 2; i++) {
            int idx = t + 256 * i;
            int row = idx >> 3;
            int col4 = (idx & 7) << 2;
            float4 d = *(const float4*)(X + (size_t)(mbase + row) * 256 + kc + col4);
            u16 e[4] = {f2bf(d.x), f2bf(d.y), f2bf(d.z), f2bf(d.w)};
            *(uint2*)&As[row][col4] = *(uint2*)e;
        }
        for (int i = 0; i < 2; i++) {
            int idx = t + 256 * i;
            int row = idx >> 3;
            int col4 = (idx & 7) << 2;
            uint2 w = *(const uint2*)(Wt + (size_t)(ntile * 64 + row) * 256 + kc + col4);
            *(uint2*)&Bts[row][col4] = w;
        }
        __syncthreads();

        bf16x8 a = *(const bf16x8*)&As[wave * 16 + l15][l4 * 8];
        for (int c = 0; c < 4; c++) {
            bf16x8 b = *(const bf16x8*)&Bts[c * 16 + l15][l4 * 8];
            acc[c] = __builtin_amdgcn_mfma_f32_16x16x32_bf16(a, b, acc[c], 0, 0, 0);
        }
    }

    if (ntile < 8) {
        const float scl = (ntile < 4) ? QSCL : 1.0f;
        for (int c = 0; c < 4; c++) {
            int colc = c * 16 + l15;
            float bv = Bias[ntile * 64 + colc];
            for (int r = 0; r < 4; r++) {
                int row = mbase + wave * 16 + l4 * 4 + r;
                QK[(size_t)row * 512 + ntile * 64 + colc] = f2bf((acc[c][r] + bv) * scl);
            }
        }
    } else {
        const int h = ntile - 8;
        for (int c = 0; c < 4; c++) {
            int d = c * 16 + l15;
            float bv = Bias[512 + h * 64 + d];
            int n = mbase + wave * 16 + l4 * 4;
            int b = n >> 12;
            int nin = n & 4095;
            u16 e[4] = {f2bf(acc[c][0] + bv), f2bf(acc[c][1] + bv),
                        f2bf(acc[c][2] + bv), f2bf(acc[c][3] + bv)};
            *(uint2*)(Vt + ((size_t)(b * 4 + h) * 64 + d) * 4096 + nin) = *(uint2*)e;
        }
    }
}

__global__ __launch_bounds__(256)
void gemm_out_old(const u16* __restrict__ Wt2, const float* __restrict__ Bias,
                  float* __restrict__ IO) {
    __shared__ __align__(16) u16 As[64][264];
    __shared__ __align__(16) u16 Wts[256][40];

    const int t = threadIdx.x;
    const int lane = t & 63;
    const int wave = t >> 6;
    const int l15 = lane & 15;
    const int l4 = lane >> 4;
    const int mbase = blockIdx.x << 6;

    for (int i = 0; i < 16; i++) {
        int idx = t + 256 * i;
        int row = idx >> 6;
        int col4 = (idx & 63) << 2;
        float4 d = *(const float4*)(IO + (size_t)(mbase + row) * 256 + col4);
        u16 e[4] = {f2bf(d.x), f2bf(d.y), f2bf(d.z), f2bf(d.w)};
        *(uint2*)&As[row][col4] = *(uint2*)e;
    }

    f32x4 acc[4][4];
    for (int nt = 0; nt < 4; nt++)
        for (int c = 0; c < 4; c++) acc[nt][c] = (f32x4){0.f, 0.f, 0.f, 0.f};

    for (int kc = 0; kc < 256; kc += 32) {
        __syncthreads();
        for (int i = 0; i < 8; i++) {
            int idx = t + 256 * i;
            int row = idx >> 3;
            int col4 = (idx & 7) << 2;
            uint2 w = *(const uint2*)(Wt2 + (size_t)row * 256 + kc + col4);
            *(uint2*)&Wts[row][col4] = w;
        }
        __syncthreads();

        bf16x8 a = *(const bf16x8*)&As[wave * 16 + l15][kc + l4 * 8];
        for (int nt = 0; nt < 4; nt++)
            for (int c = 0; c < 4; c++) {
                bf16x8 b = *(const bf16x8*)&Wts[nt * 64 + c * 16 + l15][l4 * 8];
                acc[nt][c] = __builtin_amdgcn_mfma_f32_16x16x32_bf16(a, b, acc[nt][c], 0, 0, 0);
            }
    }

    for (int nt = 0; nt < 4; nt++)
        for (int c = 0; c < 4; c++) {
            int coln = nt * 64 + c * 16 + l15;
            float bv = Bias[coln];
            for (int r = 0; r < 4; r++) {
                int row = mbase + wave * 16 + l4 * 4 + r;
                IO[(size_t)row * 256 + coln] = acc[nt][c][r] + bv;
            }
        }
}

// ===========================================================================
// NEW m97-style GEMM core (proven): global_load_lds staging, XOR-swizzled
// chunks, ds_read_b128 frags, 16 MFMA/wave/K-step.
// ===========================================================================
__global__ __launch_bounds__(256)
void gemm_qkv_new(const u16* __restrict__ Abf, const u16* __restrict__ Bt,
                  const float* __restrict__ Bias, u16* __restrict__ QK,
                  u16* __restrict__ Vt) {
    __shared__ __align__(16) u16 As[128 * 32];
    __shared__ __align__(16) u16 Bs[128 * 32];

    const int t = threadIdx.x;
    const int lane = t & 63;
    const int wave = t >> 6;
    const int l15 = lane & 15;
    const int l4 = lane >> 4;
    const int wm = wave >> 1, wn = wave & 1;

    const int mb = blockIdx.x / 6;
    const int nb = blockIdx.x % 6;

    const u16* gA[2]; const u16* gB[2]; int ldsoff[2];
    #pragma unroll
    for (int i = 0; i < 2; i++) {
        int chunk = i * 256 + t;
        int row = chunk >> 2;
        int sch = (chunk & 3) ^ (row & 3);
        gA[i] = Abf + (size_t)(mb * 128 + row) * 256 + sch * 8;
        gB[i] = Bt + (size_t)(nb * 128 + row) * 256 + sch * 8;
        ldsoff[i] = (i * 256 + wave * 64) * 8;
    }
    int offA[4], offB[4];
    #pragma unroll
    for (int c = 0; c < 4; c++) {
        offA[c] = (wm * 64 + c * 16 + l15) * 32 + ((l4 ^ (l15 & 3)) * 8);
        offB[c] = (wn * 64 + c * 16 + l15) * 32 + ((l4 ^ (l15 & 3)) * 8);
    }

    f32x4 acc[4][4];
    #pragma unroll
    for (int cm = 0; cm < 4; cm++)
        for (int cn = 0; cn < 4; cn++) acc[cm][cn] = (f32x4){0.f, 0.f, 0.f, 0.f};

    for (int kc = 0; kc < 256; kc += 32) {
        __syncthreads();
        #pragma unroll
        for (int i = 0; i < 2; i++) {
            GLD_LDS16(gA[i] + kc, As + ldsoff[i]);
            GLD_LDS16(gB[i] + kc, Bs + ldsoff[i]);
        }
        __syncthreads();

        bf16x8 a[4], b[4];
        #pragma unroll
        for (int c = 0; c < 4; c++) {
            a[c] = *(const bf16x8*)(As + offA[c]);
            b[c] = *(const bf16x8*)(Bs + offB[c]);
        }
        #pragma unroll
        for (int cm = 0; cm < 4; cm++)
            #pragma unroll
            for (int cn = 0; cn < 4; cn++)
                acc[cm][cn] = __builtin_amdgcn_mfma_f32_16x16x32_bf16(
                    a[cm], b[cn], acc[cm][cn], 0, 0, 0);
    }

    #pragma unroll
    for (int cn = 0; cn < 4; cn++) {
        int n = nb * 128 + wn * 64 + cn * 16 + l15;
        float bv = Bias[n];
        int slice = n >> 6;
        if (slice < 4) {
            #pragma unroll
            for (int cm = 0; cm < 4; cm++) {
                int m0 = mb * 128 + wm * 64 + cm * 16 + l4 * 4;
                for (int r = 0; r < 4; r++)
                    QK[(size_t)(m0 + r) * 512 + n] = f2bf((acc[cm][cn][r] + bv) * QSCL);
            }
        } else if (slice < 8) {
            #pragma unroll
            for (int cm = 0; cm < 4; cm++) {
                int m0 = mb * 128 + wm * 64 + cm * 16 + l4 * 4;
                for (int r = 0; r < 4; r++)
                    QK[(size_t)(m0 + r) * 512 + n] = f2bf(acc[cm][cn][r] + bv);
            }
        } else {
            int h = slice - 8;
            int d = n & 63;
            #pragma unroll
            for (int cm = 0; cm < 4; cm++) {
                int m0 = mb * 128 + wm * 64 + cm * 16 + l4 * 4;
                int b_ = m0 >> 12;
                int nin = m0 & 4095;
                u16 e[4] = {f2bf(acc[cm][cn][0] + bv), f2bf(acc[cm][cn][1] + bv),
                            f2bf(acc[cm][cn][2] + bv), f2bf(acc[cm][cn][3] + bv)};
                *(uint2*)(Vt + ((size_t)(b_ * 4 + h) * 64 + d) * 4096 + nin) = *(uint2*)e;
            }
        }
    }
}

__global__ __launch_bounds__(256)
void gemm_out_new(const u16* __restrict__ Obf, const u16* __restrict__ Wt2,
                  const float* __restrict__ Bias, float* __restrict__ out) {
    __shared__ __align__(16) u16 As[128 * 32];
    __shared__ __align__(16) u16 Bs[128 * 32];

    const int t = threadIdx.x;
    const int lane = t & 63;
    const int wave = t >> 6;
    const int l15 = lane & 15;
    const int l4 = lane >> 4;
    const int wm = wave >> 1, wn = wave & 1;

    const int mb = blockIdx.x >> 1;
    const int nb = blockIdx.x & 1;

    const u16* gA[2]; const u16* gB[2]; int ldsoff[2];
    #pragma unroll
    for (int i = 0; i < 2; i++) {
        int chunk = i * 256 + t;
        int row = chunk >> 2;
        int sch = (chunk & 3) ^ (row & 3);
        gA[i] = Obf + (size_t)(mb * 128 + row) * 256 + sch * 8;
        gB[i] = Wt2 + (size_t)(nb * 128 + row) * 256 + sch * 8;
        ldsoff[i] = (i * 256 + wave * 64) * 8;
    }
    int offA[4], offB[4];
    #pragma unroll
    for (int c = 0; c < 4; c++) {
        offA[c] = (wm * 64 + c * 16 + l15) * 32 + ((l4 ^ (l15 & 3)) * 8);
        offB[c] = (wn * 64 + c * 16 + l15) * 32 + ((l4 ^ (l15 & 3)) * 8);
    }

    f32x4 acc[4][4];
    #pragma unroll
    for (int cm = 0; cm < 4; cm++)
        for (int cn = 0; cn < 4; cn++) acc[cm][cn] = (f32x4){0.f, 0.f, 0.f, 0.f};

    for (int kc = 0; kc < 256; kc += 32) {
        __syncthreads();
        #pragma unroll
        for (int i = 0; i < 2; i++) {
            GLD_LDS16(gA[i] + kc, As + ldsoff[i]);
            GLD_LDS16(gB[i] + kc, Bs + ldsoff[i]);
        }
        __syncthreads();

        bf16x8 a[4], b[4];
        #pragma unroll
        for (int c = 0; c < 4; c++) {
            a[c] = *(const bf16x8*)(As + offA[c]);
            b[c] = *(const bf16x8*)(Bs + offB[c]);
        }
        #pragma unroll
        for (int cm = 0; cm < 4; cm++)
            #pragma unroll
            for (int cn = 0; cn < 4; cn++)
                acc[cm][cn] = __builtin_amdgcn_mfma_f32_16x16x32_bf16(
                    a[cm], b[cn], acc[cm][cn], 0, 0, 0);
    }

    #pragma unroll
    for (int cn = 0; cn < 4; cn++) {
        int n = nb * 128 + wn * 64 + cn * 16 + l15;
        float bv = Bias[n];
        #pragma unroll
        for (int cm = 0; cm < 4; cm++) {
            int m0 = mb * 128 + wm * 64 + cm * 16 + l4 * 4;
            for (int r = 0; r < 4; r++)
                out[(size_t)(m0 + r) * 256 + n] = acc[cm][cn][r] + bv;
        }
    }
}

// ---------------------------------------------------------------------------
// Flash attention (q-split, occupancy-tiled): 4-wave blocks, wave owns 16
// q-rows, grid nbh*64 = 1024 blocks. LDS shrunk to EXACTLY 40960 B so
// 160KB/CU = 4 blocks/CU and 1024 = 4*256 tiles perfectly (no tail — the
// R10 regression was 3/CU capacity vs 1024-block grid => 25% tail).
// Ps is unpadded [4][16][64] with a 16B-unit XOR swizzle (unit ^= l15&7,
// same row-keyed map on write and read => values round-trip; b64 writes and
// b128 reads both land on the bank-minimum).
// ---------------------------------------------------------------------------
__global__ __launch_bounds__(256, 4)
void attn_kernel(const u16* __restrict__ QK, const u16* __restrict__ Vt,
                 float* __restrict__ Of, u16* __restrict__ Obf, int writebf,
                 int bhmask, int bhbits) {
    __shared__ __align__(16) u16 Kt[2][64][64];    // [buf][j][d] swizzled 16K
    __shared__ __align__(16) u16 Vts[2][64][64];   // [buf][d][j] swizzled 16K
    __shared__ __align__(16) u16 Ps[4][16][64];    // [wave][q][j] swizzled 8K

    const int t = threadIdx.x;
    const int lane = t & 63;
    const int wave = t >> 6;
    const int l15 = lane & 15;
    const int l4 = lane >> 4;

    const int bh = blockIdx.x & bhmask;
    const int qb = blockIdx.x >> bhbits;
    const int b = bh >> 2;
    const int h = bh & 3;

    const size_t qkbase = (size_t)b * 4096 * 512;
    const size_t vtbase = (size_t)bh * 64 * 4096;
    const int q0 = qb * 64 + wave * 16;

    // hoisted staging addresses
    const u16* gk[2]; const u16* gv[2]; u16* lk[2]; u16* lv[2];
    #pragma unroll
    for (int i = 0; i < 2; i++) {
        int chunk = i * 256 + t;
        int row = chunk >> 3;
        int sch = (chunk & 7) ^ (row & 7);
        gk[i] = QK + qkbase + (size_t)row * 512 + 256 + h * 64 + sch * 8;
        gv[i] = Vt + vtbase + (size_t)row * 4096 + sch * 8;
        int cbase = (i * 256 + wave * 64) * 8;
        lk[i] = &Kt[0][0][0] + cbase;
        lv[i] = &Vts[0][0][0] + cbase;
    }
    // hoisted K/V fragment offsets
    int koff[4][2];
    #pragma unroll
    for (int c = 0; c < 4; c++) {
        int row = c * 16 + l15;
        int sw = row & 7;
        koff[c][0] = row * 64 + ((0 + l4) ^ sw) * 8;
        koff[c][1] = row * 64 + ((4 + l4) ^ sw) * 8;
    }
    // hoisted Ps offsets (16B-unit XOR swizzle, keyed by row l15)
    u16* psbase = &Ps[wave][l15][0];
    int offw[4], offr[2];
    #pragma unroll
    for (int c = 0; c < 4; c++)
        offw[c] = (((2 * c + (l4 >> 1)) ^ (l15 & 7)) << 3) + ((l4 & 1) << 2);
    #pragma unroll
    for (int kk = 0; kk < 2; kk++)
        offr[kk] = (((4 * kk + l4) ^ (l15 & 7)) << 3);

    // Q fragments (B-operand, n=q=l15), 16 q-rows per wave
    bf16x8 qf[2];
    #pragma unroll
    for (int kk = 0; kk < 2; kk++)
        qf[kk] = *(const bf16x8*)(QK + qkbase
            + (size_t)(q0 + l15) * 512 + h * 64 + kk * 32 + l4 * 8);

    f32x4 Oacc[4];
    #pragma unroll
    for (int c = 0; c < 4; c++) Oacc[c] = (f32x4){0.f, 0.f, 0.f, 0.f};
    float lsum = 0.f;

    auto stageKV = [&](int buf, int jn) {
        #pragma unroll
        for (int i = 0; i < 2; i++) {
            GLD_LDS16(gk[i] + (size_t)jn * 32768, lk[i] + buf * 4096);
            GLD_LDS16(gv[i] + jn * 64,            lv[i] + buf * 4096);
        }
    };

    auto body = [&](int par, int jn) {
        __syncthreads();          // readers done + staging of buf[par] visible
        stageKV(par ^ 1, jn);     // prefetch flies during compute

        const u16* kb = &Kt[0][0][0] + par * 4096;
        const u16* vb = &Vts[0][0][0] + par * 4096;

        // S^T: A = K rows from LDS, B = qf
        f32x4 s[4];
        #pragma unroll
        for (int c = 0; c < 4; c++) s[c] = (f32x4){0.f, 0.f, 0.f, 0.f};
        #pragma unroll
        for (int c = 0; c < 4; c++) {
            bf16x8 k0 = *(const bf16x8*)(kb + koff[c][0]);
            bf16x8 k1 = *(const bf16x8*)(kb + koff[c][1]);
            s[c] = __builtin_amdgcn_mfma_f32_16x16x32_bf16(k0, qf[0], s[c], 0, 0, 0);
            s[c] = __builtin_amdgcn_mfma_f32_16x16x32_bf16(k1, qf[1], s[c], 0, 0, 0);
        }

        // softmax: p = exp2(s); truncation-consistent lsum; perm-packed Ps
        float ls = 0.f;
        #pragma unroll
        for (int c = 0; c < 4; c++) {
            f32x4 sv = s[c];
            uint32_t u0 = fbits(__builtin_exp2f(sv[0]));
            uint32_t u1 = fbits(__builtin_exp2f(sv[1]));
            uint32_t u2 = fbits(__builtin_exp2f(sv[2]));
            uint32_t u3 = fbits(__builtin_exp2f(sv[3]));
            float t0 = bits2f(u0 & 0xFFFF0000u);
            float t1 = bits2f(u1 & 0xFFFF0000u);
            float t2 = bits2f(u2 & 0xFFFF0000u);
            float t3 = bits2f(u3 & 0xFFFF0000u);
            ls += (t0 + t1) + (t2 + t3);
            uint2 pk;
            pk.x = __builtin_amdgcn_perm(u1, u0, 0x07060302u);
            pk.y = __builtin_amdgcn_perm(u3, u2, 0x07060302u);
            *(uint2*)(psbase + offw[c]) = pk;
        }
        lsum += ls;

        __threadfence_block();    // within-wave cross-lane Ps dependency

        bf16x8 bp[2];
        #pragma unroll
        for (int kk = 0; kk < 2; kk++)
            bp[kk] = *(const bf16x8*)(psbase + offr[kk]);

        // O^T: A = V^T rows from LDS, B = P^T
        #pragma unroll
        for (int c = 0; c < 4; c++) {
            bf16x8 v0 = *(const bf16x8*)(vb + koff[c][0]);
            bf16x8 v1 = *(const bf16x8*)(vb + koff[c][1]);
            Oacc[c] = __builtin_amdgcn_mfma_f32_16x16x32_bf16(v0, bp[0], Oacc[c], 0, 0, 0);
            Oacc[c] = __builtin_amdgcn_mfma_f32_16x16x32_bf16(v1, bp[1], Oacc[c], 0, 0, 0);
        }
    };

    stageKV(0, 0);
    for (int jt = 0; jt < 64; jt += 2) {
        body(0, jt + 1);
        body(1, (jt + 2) & 63);   // wrap keeps dead last prefetch in-bounds
    }

    // epilogue: lane q = q0+l15, d = c*16 + l4*4 + r
    float l = lsum;
    l += __shfl_xor(l, 16);
    l += __shfl_xor(l, 32);
    float inv = 1.f / l;
    size_t row = (size_t)b * 4096 + q0 + l15;
    if (writebf) {
        #pragma unroll
        for (int c = 0; c < 4; c++) {
            f32x4 o = Oacc[c] * inv;
            u16 e[4] = {f2bf(o[0]), f2bf(o[1]), f2bf(o[2]), f2bf(o[3])};
            *(uint2*)(Obf + row * 256 + h * 64 + c * 16 + l4 * 4) = *(uint2*)e;
        }
    } else {
        #pragma unroll
        for (int c = 0; c < 4; c++) {
            f32x4 o = Oacc[c] * inv;
            *(f32x4*)(Of + row * 256 + h * 64 + c * 16 + l4 * 4) = o;
        }
    }
}

// ---------------------------------------------------------------------------
extern "C" void kernel_launch(void* const* d_in, const int* in_sizes, int n_in,
                              void* d_out, int out_size, void* d_ws, size_t ws_size,
                              hipStream_t stream) {
    const float* x     = (const float*)d_in[0];  // [16384,256]
    const float* w_qkv = (const float*)d_in[1];  // [256,768]
    const float* b_qkv = (const float*)d_in[2];  // [768]
    const float* w_out = (const float*)d_in[3];  // [256,256]
    const float* b_out = (const float*)d_in[4];  // [256]
    float* out = (float*)d_out;                  // [16384,256] fp32

    char* ws = (char*)d_ws;
    u16* Wt  = (u16*)ws;                             // [768][256]   393216 B
    u16* Wt2 = (u16*)(ws + 393216);                  // [256][256]   131072 B
    u16* QK  = (u16*)(ws + 524288);                  // [16384][512] 16.78 MB
    u16* Vt  = (u16*)(ws + 524288 + 16777216);       // [16][64][4096] 8.39 MB
    u16* XO  = (u16*)(ws + 524288 + 16777216 + 8388608);  // xbf/Obf shared 8.39 MB
    const size_t NEED_NEW = 524288 + 16777216 + 8388608 + 8388608; // 34.08 MB

    transpose_kernel<<<dim3(48), dim3(256), 0, stream>>>(w_qkv, Wt, 256, 12);
    transpose_kernel<<<dim3(16), dim3(256), 0, stream>>>(w_out, Wt2, 256, 4);

    if (ws_size >= NEED_NEW) {
        convert_kernel<<<dim3(4096), dim3(256), 0, stream>>>(x, XO);
        gemm_qkv_new<<<dim3(768), dim3(256), 0, stream>>>(XO, Wt, b_qkv, QK, Vt);
        attn_kernel<<<dim3(1024), dim3(256), 0, stream>>>(
            QK, Vt, out, XO, 1, 15, 4);
        gemm_out_new<<<dim3(256), dim3(256), 0, stream>>>(XO, Wt2, b_out, out);
    } else {
        // fallback (proven 25.7 MB layout): old GEMMs, attn writes fp32
        gemm_qkv_old<<<dim3(3072), dim3(256), 0, stream>>>(x, Wt, b_qkv, QK, Vt);
        attn_kernel<<<dim3(1024), dim3(256), 0, stream>>>(
            QK, Vt, out, (u16*)nullptr, 0, 15, 4);
        gemm_out_old<<<dim3(256), dim3(256), 0, stream>>>(Wt2, b_out, out);
    }
}